// Round 9
// baseline (1247.879 us; speedup 1.0000x reference)
//
#include <hip/hip_runtime.h>
#include <math.h>

#define G 8192
#define D 1024
#define E 64
#define CAP 160
#define SLAB (E*CAP)                      // 10240 floats per token per tensor
#define OFF_COMB ((size_t)G*SLAB)         // 83886080
#define OFF_LOSS ((size_t)2*(size_t)G*SLAB)
#define OFF_M1 (OFF_LOSS+1)
#define OFF_M2 (OFF_M1+64)

typedef float vf4 __attribute__((ext_vector_type(4)));   // native vector for nt stores

// workspace element offsets (4B elements)
#define W_E1 0
#define W_E2 8192
#define W_G1 32768
#define W_G2 40960
#define W_SP   57408                      // 512 gating blocks * 64 floats
#define W_FLAG 131072                     // 512 gating done-flags
#define W_ZFLAG 139264                    // 8192 per-token zero done-flags
#define MAGIC 0x13371337                  // != 0xAA poison and != 0 -> init-agnostic

#define NGATE 512
#define NZERO 8192

// ---------------- Single fused kernel ----------------
// grid 8704 x 256:
//   [0,512):    gating GEMM+softmax+top2 (16 tok/block); release per-block flag.
//   [512,8704): zero block = 1 token: nt-zero its 2 slabs (80 KB), release per-token
//               flag. Blocks with (token&255)==255 (LAST-dispatched of their chunk ->
//               chunk-mates already resident/retired -> no deadlock) become that
//               chunk's EPI WORKER: poll 512 gating flags (set ~45us, instant) +
//               their chunk's 256 zero flags (chunk-local, ~instant), rebuild global
//               chunk histograms/prefix/c1k in LDS, rank own chunk, scatter <=4
//               nonzeros/token. Worker of chunk 0 also writes loss + counts.
// Only 32 pollers total (vs R8's 2048x256 storm). Epi overlaps the zero drain.
__global__ __launch_bounds__(256) void k_fused(const float* __restrict__ x,
                                               const float* __restrict__ w,
                                               int* __restrict__ wsi,
                                               float* __restrict__ wsf,
                                               float* __restrict__ out) {
  __shared__ float xs[16][64];            // gating staging (4 KB)
  __shared__ float sp[256];               // gating/loss partials (1 KB)
  __shared__ int h[32][64];               // worker histograms, reused for E1 then E2 (8 KB)
  __shared__ int hw1[4][64], hw2[4][64];  // per-wave own-chunk histograms (2 KB)
  __shared__ int base1_s[64], base2_s[64], c1k_s[64], run1_s[64], run2_s[64];

  const int t = threadIdx.x;

  if (blockIdx.x >= NGATE) {
    // ================= zero path (1 token) =================
    const int n = blockIdx.x - NGATE;
    vf4 z = {0.f, 0.f, 0.f, 0.f};
    vf4* __restrict__ dp = (vf4*)out + (size_t)n * (SLAB/4);
    vf4* __restrict__ cp = (vf4*)(out + OFF_COMB) + (size_t)n * (SLAB/4);
#pragma unroll
    for (int i = 0; i < 10; ++i) {        // 2560 vf4 per tensor = full 10240-float slab
      const int idx = i * 256 + t;
      __builtin_nontemporal_store(z, &dp[idx]);
      __builtin_nontemporal_store(z, &cp[idx]);
    }
    __syncthreads();                      // all lanes' stores drained (vmcnt0 at barrier)
    if (t == 0) {
      __threadfence();
      __hip_atomic_store(&wsi[W_ZFLAG + n], MAGIC,
                         __ATOMIC_RELEASE, __HIP_MEMORY_SCOPE_AGENT);
    }
    if ((n & 255) != 255) return;

    // ================= epi worker for chunk b =================
    const int b = n >> 8;
    // gating flags (long since set — expect first-poll success)
    for (;;) {
      int done = 1;
      for (int i = t; i < NGATE; i += 256)
        if (__hip_atomic_load(&wsi[W_FLAG + i], __ATOMIC_ACQUIRE,
                              __HIP_MEMORY_SCOPE_AGENT) != MAGIC) done = 0;
      if (__syncthreads_and(done)) break;
      __builtin_amdgcn_s_sleep(2);
    }
    // own chunk's zero flags (chunk-mates dispatched before us)
    for (;;) {
      int done = (__hip_atomic_load(&wsi[W_ZFLAG + b * 256 + t], __ATOMIC_ACQUIRE,
                                    __HIP_MEMORY_SCOPE_AGENT) == MAGIC);
      if (__syncthreads_and(done)) break;
      __builtin_amdgcn_s_sleep(2);
    }

    const int lane = t & 63, wv = t >> 6;

    // pass 1: top-1 histograms over all chunks
    for (int i = t; i < 32 * 64; i += 256) ((int*)h)[i] = 0;
    if (t < 64) { for (int i = 0; i < 4; ++i) { hw1[i][t] = 0; hw2[i][t] = 0; } }
    __syncthreads();
    int my_e1 = 0, my_e2 = 0;
    for (int cc = 0; cc < 32; ++cc) {
      const int a = wsi[W_E1 + cc * 256 + t];
      if (cc == b) my_e1 = a;
      atomicAdd(&h[cc][a], 1);
    }
    __syncthreads();
    if (t < 64) {
      int r = 0, b1 = 0;
      for (int cc = 0; cc < 32; ++cc) { if (cc == b) b1 = r; r += h[cc][t]; }
      base1_s[t] = b1; run1_s[t] = r; c1k_s[t] = min(r, CAP);
    }
    __syncthreads();
    // pass 2: top-2 histograms
    for (int i = t; i < 32 * 64; i += 256) ((int*)h)[i] = 0;
    __syncthreads();
    for (int cc = 0; cc < 32; ++cc) {
      const int a = wsi[W_E2 + cc * 256 + t];
      if (cc == b) my_e2 = a;
      atomicAdd(&h[cc][a], 1);
    }
    __syncthreads();
    if (t < 64) {
      int r = 0, b2 = 0;
      for (int cc = 0; cc < 32; ++cc) { if (cc == b) b2 = r; r += h[cc][t]; }
      base2_s[t] = b2; run2_s[t] = r;
    }

    // intra-chunk ranks (wave shuffles + per-wave histograms)
    int c1 = 0, c2 = 0;
    for (int j = 0; j < 64; ++j) {
      int ja = __shfl(my_e1, j, 64);
      int jb = __shfl(my_e2, j, 64);
      if (j < lane) { c1 += (ja == my_e1); c2 += (jb == my_e2); }
    }
    atomicAdd(&hw1[wv][my_e1], 1);
    atomicAdd(&hw2[wv][my_e2], 1);
    __syncthreads();
    for (int ww = 0; ww < wv; ++ww) { c1 += hw1[ww][my_e1]; c2 += hw2[ww][my_e2]; }

    // scatter own chunk (slabs of this chunk all zeroed: flags acquired above)
    const int tok = b * 256 + t;
    const int p1 = base1_s[my_e1] + c1;
    const int p2 = base2_s[my_e2] + c2 + c1k_s[my_e2];
    const float g1 = wsf[W_G1 + tok];
    const float g2 = wsf[W_G2 + tok];
    const size_t base = (size_t)tok * SLAB;
    // combine entry exists iff position < CAP and gate nonzero
    // (dispatch = (combine != 0), so gate underflow-to-0 must kill dispatch too)
    if (p1 < CAP && g1 != 0.0f) {
      out[base + my_e1 * CAP + p1] = 1.0f;
      out[OFF_COMB + base + my_e1 * CAP + p1] = g1;
    }
    if (p2 < CAP && g2 != 0.0f) {
      out[base + my_e2 * CAP + p2] = 1.0f;
      out[OFF_COMB + base + my_e2 * CAP + p2] = g2;
    }

    if (b != 0) return;

    // counts
    if (t < 64) {
      out[OFF_M1 + t] = (float)c1k_s[t];
      out[OFF_M2 + t] = (float)min(run2_s[t], max(0, CAP - c1k_s[t]));
    }
    // loss = mean_e( (sumprob_e/8192) * (run1_e/8192) ) * 64^2
    {
      const int e = t & 63, q = t >> 6;
      float s = 0.f;
      for (int i = 0; i < 128; ++i)
        s += wsf[W_SP + (size_t)(q * 128 + i) * 64 + e];
      sp[t] = s;
    }
    __syncthreads();
    if (t < 64) {
      float s = sp[t] + sp[64 + t] + sp[128 + t] + sp[192 + t];
      float term = (s * (1.0f/8192.f)) * ((float)run1_s[t] * (1.0f/8192.f));
      for (int off = 32; off > 0; off >>= 1) term += __shfl_xor(term, off, 64);
      if (t == 0) out[OFF_LOSS] = (term * (1.0f/64.f)) * 4096.0f;
    }
    return;
  }

  // ================= gating path =================
  const int lane = t & 63;
  const int wid  = t >> 6;
  const int nblk = blockIdx.x * 16;      // 16 tokens per block
  const int n0   = nblk + wid * 4;       // 4 tokens per wave

  float acc[4] = {0.f, 0.f, 0.f, 0.f};

  const int stok = t >> 4;               // 0..15 (staging token)
  const int sk   = (t & 15) * 4;         // 0..60 (staging k offset)
  const float* xsrc = x + (size_t)(nblk + stok) * D + sk;

  for (int kc = 0; kc < D; kc += 64) {
    *(float4*)&xs[stok][sk] = *(const float4*)(xsrc + kc);
    float wr[64];
#pragma unroll
    for (int j = 0; j < 64; ++j) wr[j] = w[(size_t)(kc + j) * E + lane];
    __syncthreads();
#pragma unroll
    for (int tt = 0; tt < 4; ++tt) {
      const int tok = wid * 4 + tt;
      float a = acc[tt];
#pragma unroll
      for (int j4 = 0; j4 < 16; ++j4) {
        const float4 xv = *(const float4*)&xs[tok][j4 * 4];   // broadcast b128
        a = fmaf(xv.x, wr[j4*4+0], a);
        a = fmaf(xv.y, wr[j4*4+1], a);
        a = fmaf(xv.z, wr[j4*4+2], a);
        a = fmaf(xv.w, wr[j4*4+3], a);
      }
      acc[tt] = a;
    }
    __syncthreads();
  }

  float ps = 0.f;
  for (int tt = 0; tt < 4; ++tt) {
    float v = acc[tt];
    // top-1 (stable: lowest index on ties, matches jax.lax.top_k)
    float m = v; int mi = lane;
    for (int off = 32; off > 0; off >>= 1) {
      float ov = __shfl_xor(m, off, 64);
      int   oi = __shfl_xor(mi, off, 64);
      if (ov > m || (ov == m && oi < mi)) { m = ov; mi = oi; }
    }
    // top-2
    float v2 = (lane == mi) ? -__builtin_inff() : v;
    float m2 = v2; int mi2 = lane;
    for (int off = 32; off > 0; off >>= 1) {
      float ov = __shfl_xor(m2, off, 64);
      int   oi = __shfl_xor(mi2, off, 64);
      if (ov > m2 || (ov == m2 && oi < mi2)) { m2 = ov; mi2 = oi; }
    }
    float ex = expf(v - m);
    float den = ex;
    for (int off = 32; off > 0; off >>= 1) den += __shfl_xor(den, off, 64);
    ps += ex / den;

    float g1 = 1.0f / den;            // exp(0)/den
    float g2 = expf(m2 - m) / den;
    float s  = g1 + g2 + 1e-9f;
    float ga = g1 / s, gb = g2 / s;
    if (lane == 0) {
      int n = n0 + tt;
      wsi[W_E1 + n] = mi;
      wsi[W_E2 + n] = mi2;
      wsf[W_G1 + n] = ga;
      wsf[W_G2 + n] = gb;
    }
  }
  sp[t] = ps;
  __syncthreads();
  if (t < 64) {
    wsf[W_SP + blockIdx.x * 64 + t] =
      sp[t] + sp[64 + t] + sp[128 + t] + sp[192 + t];
  }
  __syncthreads();
  if (t == 0) {
    __threadfence();   // publish E1/E2/G1/G2/SP device-wide
    __hip_atomic_store(&wsi[W_FLAG + blockIdx.x], MAGIC,
                       __ATOMIC_RELEASE, __HIP_MEMORY_SCOPE_AGENT);
  }
}

extern "C" void kernel_launch(void* const* d_in, const int* in_sizes, int n_in,
                              void* d_out, int out_size, void* d_ws, size_t ws_size,
                              hipStream_t stream) {
  const float* x = (const float*)d_in[0];
  const float* w = (const float*)d_in[1];
  float* out = (float*)d_out;
  int*   wsi = (int*)d_ws;
  float* wsf = (float*)d_ws;

  k_fused<<<NGATE + NZERO, 256, 0, stream>>>(x, w, wsi, wsf, out);
}

// Round 10
// 703.135 us; speedup vs baseline: 1.7747x; 1.7747x over previous
//
#include <hip/hip_runtime.h>
#include <math.h>

#define G 8192
#define D 1024
#define E 64
#define CAP 160
#define SLAB (E*CAP)                      // 10240 floats per token per tensor
#define OFF_COMB ((size_t)G*SLAB)         // 83886080
#define OFF_LOSS ((size_t)2*(size_t)G*SLAB)
#define OFF_M1 (OFF_LOSS+1)
#define OFF_M2 (OFF_M1+64)

typedef float vf4 __attribute__((ext_vector_type(4)));   // native vector for nt stores

// workspace element offsets (4B elements)
#define W_E1 0
#define W_E2 8192
#define W_G1 32768
#define W_G2 40960
#define W_SP  (49152+8192+64)             // 512 gating blocks * 64 floats

#define NGATE 512
#define NZERO 2048                        // 4 tokens per zero block

// ---------------- Kernel 1 (fused): gating GEMM+softmax+top2  ||  zero-fill ----------------
// grid 2560 blocks x 256 thr.
//   blocks [0,512):    gating — 16 tokens/block, wave = 64 lanes (lane<->expert), 4 tokens/wave
//   blocks [512,2560): nontemporal zero-fill of FOUR tokens' dispatch+combine slabs
//                      (2 x 160 KB contiguous streams; 40 vf4/thread/tensor).
// NO cross-block sync / fences inside the kernel (R7/R8/R9 showed agent-scope
// release+fence per block collapses write BW on non-coherent XCD L2s).
// Zero-fill (~107us HBM writes) and gating (~45us VALU/LDS) co-schedule -> max not sum.
__global__ __launch_bounds__(256) void k_gate_zero(const float* __restrict__ x,
                                                   const float* __restrict__ w,
                                                   int* __restrict__ wsi,
                                                   float* __restrict__ wsf,
                                                   float* __restrict__ out) {
  __shared__ float xs[16][64];
  __shared__ float sp[256];

  const int t = threadIdx.x;

  if (blockIdx.x >= NGATE) {
    // ---- zero path: 4 tokens, contiguous ----
    const int n0 = (blockIdx.x - NGATE) * 4;
    vf4 z = {0.f, 0.f, 0.f, 0.f};
    vf4* __restrict__ dp = (vf4*)out + (size_t)n0 * (SLAB/4);
    vf4* __restrict__ cp = (vf4*)(out + OFF_COMB) + (size_t)n0 * (SLAB/4);
    // 4 tokens * 2560 vf4 = 10240 vf4 per tensor; 40 per thread per tensor
#pragma unroll
    for (int i = 0; i < 40; ++i) {
      const int idx = i * 256 + t;
      __builtin_nontemporal_store(z, &dp[idx]);
      __builtin_nontemporal_store(z, &cp[idx]);
    }
    return;
  }

  // ---- gating path ----
  const int lane = t & 63;
  const int wid  = t >> 6;
  const int nblk = blockIdx.x * 16;      // 16 tokens per block
  const int n0   = nblk + wid * 4;       // 4 tokens per wave

  float acc[4] = {0.f, 0.f, 0.f, 0.f};

  const int stok = t >> 4;               // 0..15 (staging token)
  const int sk   = (t & 15) * 4;         // 0..60 (staging k offset)
  const float* xsrc = x + (size_t)(nblk + stok) * D + sk;

  for (int kc = 0; kc < D; kc += 64) {
    *(float4*)&xs[stok][sk] = *(const float4*)(xsrc + kc);
    float wr[64];
#pragma unroll
    for (int j = 0; j < 64; ++j) wr[j] = w[(size_t)(kc + j) * E + lane];
    __syncthreads();
#pragma unroll
    for (int tt = 0; tt < 4; ++tt) {
      const int tok = wid * 4 + tt;
      float a = acc[tt];
#pragma unroll
      for (int j4 = 0; j4 < 16; ++j4) {
        const float4 xv = *(const float4*)&xs[tok][j4 * 4];   // broadcast b128
        a = fmaf(xv.x, wr[j4*4+0], a);
        a = fmaf(xv.y, wr[j4*4+1], a);
        a = fmaf(xv.z, wr[j4*4+2], a);
        a = fmaf(xv.w, wr[j4*4+3], a);
      }
      acc[tt] = a;
    }
    __syncthreads();
  }

  float ps = 0.f;
  for (int tt = 0; tt < 4; ++tt) {
    float v = acc[tt];
    // top-1 (stable: lowest index on ties, matches jax.lax.top_k)
    float m = v; int mi = lane;
    for (int off = 32; off > 0; off >>= 1) {
      float ov = __shfl_xor(m, off, 64);
      int   oi = __shfl_xor(mi, off, 64);
      if (ov > m || (ov == m && oi < mi)) { m = ov; mi = oi; }
    }
    // top-2
    float v2 = (lane == mi) ? -__builtin_inff() : v;
    float m2 = v2; int mi2 = lane;
    for (int off = 32; off > 0; off >>= 1) {
      float ov = __shfl_xor(m2, off, 64);
      int   oi = __shfl_xor(mi2, off, 64);
      if (ov > m2 || (ov == m2 && oi < mi2)) { m2 = ov; mi2 = oi; }
    }
    float ex = expf(v - m);
    float den = ex;
    for (int off = 32; off > 0; off >>= 1) den += __shfl_xor(den, off, 64);
    ps += ex / den;

    float g1 = 1.0f / den;            // exp(0)/den
    float g2 = expf(m2 - m) / den;
    float s  = g1 + g2 + 1e-9f;
    float ga = g1 / s, gb = g2 / s;
    if (lane == 0) {
      int n = n0 + tt;
      wsi[W_E1 + n] = mi;
      wsi[W_E2 + n] = mi2;
      wsf[W_G1 + n] = ga;
      wsf[W_G2 + n] = gb;
    }
  }
  sp[t] = ps;
  __syncthreads();
  if (t < 64) {
    wsf[W_SP + blockIdx.x * 64 + t] =
      sp[t] + sp[64 + t] + sp[128 + t] + sp[192 + t];
  }
}

// ---------------- Kernel 2 (fused epilogue): rank + scan + scatter + loss/counts ----------------
// 32 blocks x 256 thr; block b owns chunk b (tokens b*256..b*256+255).
// Every block REDUNDANTLY builds all 32 chunk histograms in LDS (no cross-block
// communication -> no XCD coherence hazard; kernel boundary provides ordering),
// scans them for its own bases + c1k, ranks its own chunk via wave shuffles,
// scatters <=4 nonzeros per token. Block 0 additionally writes loss and counts.
__global__ __launch_bounds__(256) void k_epi(const int* __restrict__ wsi,
                                             const float* __restrict__ wsf,
                                             float* __restrict__ out) {
  __shared__ int h1[32][64], h2[32][64];      // 16 KB: chunk x expert histograms
  __shared__ int hw1[4][64], hw2[4][64];      // per-wave own-chunk histograms
  __shared__ int base1_s[64], base2_s[64], c1k_s[64], run1_s[64], run2_s[64];
  __shared__ float spf[256];

  const int b = blockIdx.x, t = threadIdx.x;
  const int lane = t & 63, w = t >> 6;

  for (int i = t; i < 32 * 64; i += 256) { ((int*)h1)[i] = 0; ((int*)h2)[i] = 0; }
  if (t < 64) { for (int i = 0; i < 4; ++i) { hw1[i][t] = 0; hw2[i][t] = 0; } }
  __syncthreads();

  // all-chunk histograms (redundant per block); capture own token's experts on the way
  int my_e1 = 0, my_e2 = 0;
  for (int cc = 0; cc < 32; ++cc) {
    const int n = cc * 256 + t;
    const int a  = wsi[W_E1 + n];
    const int bb = wsi[W_E2 + n];
    if (cc == b) { my_e1 = a; my_e2 = bb; }
    atomicAdd(&h1[cc][a], 1);
    atomicAdd(&h2[cc][bb], 1);
  }
  __syncthreads();

  // per-expert totals + exclusive base at own chunk (threads 0..127)
  if (t < 64) {
    int r1 = 0, b1 = 0;
    for (int cc = 0; cc < 32; ++cc) { if (cc == b) b1 = r1; r1 += h1[cc][t]; }
    base1_s[t] = b1; run1_s[t] = r1; c1k_s[t] = min(r1, CAP);
  } else if (t < 128) {
    const int e = t - 64;
    int r2 = 0, b2 = 0;
    for (int cc = 0; cc < 32; ++cc) { if (cc == b) b2 = r2; r2 += h2[cc][e]; }
    base2_s[e] = b2; run2_s[e] = r2;
  }

  // intra-chunk ranks for own chunk (wave shuffles + per-wave histograms)
  int c1 = 0, c2 = 0;
  for (int j = 0; j < 64; ++j) {
    int ja = __shfl(my_e1, j, 64);
    int jb = __shfl(my_e2, j, 64);
    if (j < lane) { c1 += (ja == my_e1); c2 += (jb == my_e2); }
  }
  atomicAdd(&hw1[w][my_e1], 1);
  atomicAdd(&hw2[w][my_e2], 1);
  __syncthreads();
  for (int ww = 0; ww < w; ++ww) { c1 += hw1[ww][my_e1]; c2 += hw2[ww][my_e2]; }

  // scatter
  const int n = b * 256 + t;
  const int p1 = base1_s[my_e1] + c1;
  const int p2 = base2_s[my_e2] + c2 + c1k_s[my_e2];
  const float g1 = wsf[W_G1 + n];
  const float g2 = wsf[W_G2 + n];
  const size_t base = (size_t)n * SLAB;
  // combine entry exists iff position < CAP and gate nonzero
  // (dispatch = (combine != 0), so g2 underflow-to-0 must kill dispatch too)
  if (p1 < CAP && g1 != 0.0f) {
    out[base + my_e1 * CAP + p1] = 1.0f;
    out[OFF_COMB + base + my_e1 * CAP + p1] = g1;
  }
  if (p2 < CAP && g2 != 0.0f) {
    out[base + my_e2 * CAP + p2] = 1.0f;
    out[OFF_COMB + base + my_e2 * CAP + p2] = g2;
  }

  if (b != 0) return;

  // counts
  if (t < 64) {
    out[OFF_M1 + t] = (float)c1k_s[t];
    out[OFF_M2 + t] = (float)min(run2_s[t], max(0, CAP - c1k_s[t]));
  }

  // loss = mean_e( (sumprob_e/8192) * (run1_e/8192) ) * 64^2
  {
    const int e = t & 63, q = t >> 6;
    float s = 0.f;
    for (int i = 0; i < 128; ++i)
      s += wsf[W_SP + (size_t)(q * 128 + i) * 64 + e];
    spf[t] = s;
  }
  __syncthreads();
  if (t < 64) {
    float s = spf[t] + spf[64 + t] + spf[128 + t] + spf[192 + t];
    float term = (s * (1.0f/8192.f)) * ((float)run1_s[t] * (1.0f/8192.f));
    for (int off = 32; off > 0; off >>= 1) term += __shfl_xor(term, off, 64);
    if (t == 0) out[OFF_LOSS] = (term * (1.0f/64.f)) * 4096.0f;
  }
}

extern "C" void kernel_launch(void* const* d_in, const int* in_sizes, int n_in,
                              void* d_out, int out_size, void* d_ws, size_t ws_size,
                              hipStream_t stream) {
  const float* x = (const float*)d_in[0];
  const float* w = (const float*)d_in[1];
  float* out = (float*)d_out;
  int*   wsi = (int*)d_ws;
  float* wsf = (float*)d_ws;

  k_gate_zero<<<NGATE + NZERO, 256, 0, stream>>>(x, w, wsi, wsf, out);
  k_epi      <<<32, 256, 0, stream>>>(wsi, wsf, out);
}